// Round 5
// baseline (462.800 us; speedup 1.0000x reference)
//
#include <hip/hip_runtime.h>

#define NROWS 8192      // 128 sequences * 64 positions
#define BCS   136       // Bs/Cs LDS row stride (elements, padded)
#define XMS   72        // XsT/Ms LDS row stride (elements, padded)

typedef __attribute__((ext_vector_type(8))) short bf16x8;
typedef __attribute__((ext_vector_type(4))) float f32x4;

__device__ __forceinline__ float bf2f(unsigned short u) {
    union { unsigned int i; float f; } v; v.i = ((unsigned int)u) << 16; return v.f;
}
__device__ __forceinline__ unsigned short f2bf(float f) {
    union { float f; unsigned int i; } v; v.f = f;
    unsigned int r = v.i + 0x7FFFu + ((v.i >> 16) & 1u);
    return (unsigned short)(r >> 16);
}

// async global->LDS, 16B per lane; lane's LDS slot must be wave-base + lane*16.
__device__ __forceinline__ void async_lds16(const unsigned short* g, unsigned short* l) {
    __builtin_amdgcn_global_load_lds(
        (const __attribute__((address_space(1))) unsigned int*)g,
        (__attribute__((address_space(3))) unsigned int*)l, 16, 0, 0);
}

// fp32 -> bf16 conversion, 4 elements/thread
__global__ void cvt_bf16(const float* __restrict__ s, unsigned short* __restrict__ d, int n4)
{
    int i = blockIdx.x * 256 + threadIdx.x;
    if (i >= n4) return;
    float4 v = *(const float4*)(s + (size_t)i * 4);
    ushort4 o;
    o.x = f2bf(v.x); o.y = f2bf(v.y); o.z = f2bf(v.z); o.w = f2bf(v.w);
    *(ushort4*)(d + (size_t)i * 4) = o;
}

// ---------------------------------------------------------------------------
// In-proj GEMM with fused conv+SiLU epilogue.
// C[m,n] = sum_k A[m,k]*B[n,k], M=8192, N=2304, K=512.
// nB<1024  -> z columns, written raw bf16 to zbuf (ld 1024).
// nB>=1024 -> xBC columns: each wave's 64x64 acc = one full sequence (64 t);
//             stage acc->LDS bf16, causal conv(4)+bias+SiLU, write xbc (ld 1280).
// ---------------------------------------------------------------------------
__global__ __launch_bounds__(256) void gemm_inproj(
    const unsigned short* __restrict__ A, const unsigned short* __restrict__ B,
    unsigned short* __restrict__ zbuf, unsigned short* __restrict__ xbc,
    const float* __restrict__ cw, const float* __restrict__ cb)
{
    __shared__ unsigned short As[128 * 32];
    __shared__ unsigned short Bs[128 * 32];
    __shared__ unsigned short Sc[4][64 * 68];   // per-wave acc tile (bf16)
    const int tid = threadIdx.x, wave = tid >> 6, lane = tid & 63;
    const int mB = blockIdx.x * 128, nB = blockIdx.y * 128;
    const int wm = (wave >> 1) * 64, wn = (wave & 1) * 64;
    const int lr = lane & 15, lq = lane >> 4;
    const int s0 = wave * 64 + lane, s1 = s0 + 256;
    const int row0 = s0 >> 2, q0 = (s0 & 3) ^ ((row0 >> 1) & 3);
    const int row1 = s1 >> 2, q1 = (s1 & 3) ^ ((row1 >> 1) & 3);
    const unsigned short* Ag0 = A + (size_t)(mB + row0) * 512 + q0 * 8;
    const unsigned short* Ag1 = A + (size_t)(mB + row1) * 512 + q1 * 8;
    const unsigned short* Bg0 = B + (size_t)(nB + row0) * 512 + q0 * 8;
    const unsigned short* Bg1 = B + (size_t)(nB + row1) * 512 + q1 * 8;
    unsigned short* lA0 = As + s0 * 8; unsigned short* lA1 = As + s1 * 8;
    unsigned short* lB0 = Bs + s0 * 8; unsigned short* lB1 = Bs + s1 * 8;
    const int sw = (lq ^ ((lr >> 1) & 3)) * 8;
    int aoff[4], boff[4];
#pragma unroll
    for (int i = 0; i < 4; ++i) {
        aoff[i] = (wm + i * 16 + lr) * 32 + sw;
        boff[i] = (wn + i * 16 + lr) * 32 + sw;
    }
    f32x4 zero4 = {0.f,0.f,0.f,0.f};
    f32x4 acc[4][4] = {{zero4,zero4,zero4,zero4},{zero4,zero4,zero4,zero4},
                       {zero4,zero4,zero4,zero4},{zero4,zero4,zero4,zero4}};
    for (int k0 = 0; k0 < 512; k0 += 32) {
        async_lds16(Ag0 + k0, lA0);
        async_lds16(Ag1 + k0, lA1);
        async_lds16(Bg0 + k0, lB0);
        async_lds16(Bg1 + k0, lB1);
        __syncthreads();
        bf16x8 a[4], b[4];
#pragma unroll
        for (int i = 0; i < 4; ++i) a[i] = *(const bf16x8*)(As + aoff[i]);
#pragma unroll
        for (int i = 0; i < 4; ++i) b[i] = *(const bf16x8*)(Bs + boff[i]);
#pragma unroll
        for (int mi = 0; mi < 4; ++mi)
#pragma unroll
            for (int ni = 0; ni < 4; ++ni)
                acc[mi][ni] = __builtin_amdgcn_mfma_f32_16x16x32_bf16(
                    a[mi], b[ni], acc[mi][ni], 0, 0, 0);
        __syncthreads();
    }
    const int rbase = lq * 4;
    if (nB < 1024) {
        // z columns: plain bf16 store
#pragma unroll
        for (int mi = 0; mi < 4; ++mi)
#pragma unroll
            for (int ni = 0; ni < 4; ++ni) {
                int col = nB + wn + ni * 16 + lr;
#pragma unroll
                for (int r = 0; r < 4; ++r) {
                    int row = mB + wm + mi * 16 + rbase + r;
                    zbuf[(size_t)row * 1024 + col] = f2bf(acc[mi][ni][r]);
                }
            }
    } else {
        // xBC columns: conv+SiLU epilogue. Wave covers one full sequence.
        unsigned short* S = &Sc[wave][0];
#pragma unroll
        for (int mi = 0; mi < 4; ++mi)
#pragma unroll
            for (int ni = 0; ni < 4; ++ni)
#pragma unroll
                for (int r = 0; r < 4; ++r)
                    S[(mi * 16 + rbase + r) * 68 + ni * 16 + lr] = f2bf(acc[mi][ni][r]);
        __syncthreads();
        const int seq = (mB + wm) >> 6;
        unsigned short* dst = xbc + (size_t)seq * 64 * 1280;
#pragma unroll
        for (int ni = 0; ni < 4; ++ni) {
            int cn = ni * 16 + lr;                 // col within wave tile
            int cg = nB - 1024 + wn + cn;          // xBC channel 0..1279
            float4 w4 = *(const float4*)(cw + (size_t)cg * 4);
            float cbv = cb[cg];
#pragma unroll
            for (int mi = 0; mi < 4; ++mi)
#pragma unroll
                for (int r = 0; r < 4; ++r) {
                    int t = mi * 16 + rbase + r;
                    float a2 = cbv;
#pragma unroll
                    for (int k = 0; k < 4; ++k) {
                        int ts = t + k - 3;
                        if (ts >= 0)
                            a2 += bf2f(S[ts * 68 + cn]) * ((const float*)&w4)[k];
                    }
                    dst[(size_t)t * 1280 + cg] = f2bf(a2 / (1.f + __expf(-a2)));
                }
        }
    }
}

// ---------------------------------------------------------------------------
// Generic 128x128 GEMM-BT (out-proj): C = A·B^T, bf16 out.
// ---------------------------------------------------------------------------
__global__ __launch_bounds__(256) void gemm128_bt(
    const unsigned short* __restrict__ A, const unsigned short* __restrict__ B,
    unsigned short* __restrict__ C, int K, int lda, int ldb, int ldc)
{
    __shared__ unsigned short As[128 * 32];
    __shared__ unsigned short Bs[128 * 32];
    const int tid = threadIdx.x, wave = tid >> 6, lane = tid & 63;
    const int mB = blockIdx.x * 128, nB = blockIdx.y * 128;
    const int wm = (wave >> 1) * 64, wn = (wave & 1) * 64;
    const int lr = lane & 15, lq = lane >> 4;
    const int s0 = wave * 64 + lane, s1 = s0 + 256;
    const int row0 = s0 >> 2, q0 = (s0 & 3) ^ ((row0 >> 1) & 3);
    const int row1 = s1 >> 2, q1 = (s1 & 3) ^ ((row1 >> 1) & 3);
    const unsigned short* Ag0 = A + (size_t)(mB + row0) * lda + q0 * 8;
    const unsigned short* Ag1 = A + (size_t)(mB + row1) * lda + q1 * 8;
    const unsigned short* Bg0 = B + (size_t)(nB + row0) * ldb + q0 * 8;
    const unsigned short* Bg1 = B + (size_t)(nB + row1) * ldb + q1 * 8;
    unsigned short* lA0 = As + s0 * 8; unsigned short* lA1 = As + s1 * 8;
    unsigned short* lB0 = Bs + s0 * 8; unsigned short* lB1 = Bs + s1 * 8;
    const int sw = (lq ^ ((lr >> 1) & 3)) * 8;
    int aoff[4], boff[4];
#pragma unroll
    for (int i = 0; i < 4; ++i) {
        aoff[i] = (wm + i * 16 + lr) * 32 + sw;
        boff[i] = (wn + i * 16 + lr) * 32 + sw;
    }
    f32x4 zero4 = {0.f,0.f,0.f,0.f};
    f32x4 acc[4][4] = {{zero4,zero4,zero4,zero4},{zero4,zero4,zero4,zero4},
                       {zero4,zero4,zero4,zero4},{zero4,zero4,zero4,zero4}};
    for (int k0 = 0; k0 < K; k0 += 32) {
        async_lds16(Ag0 + k0, lA0);
        async_lds16(Ag1 + k0, lA1);
        async_lds16(Bg0 + k0, lB0);
        async_lds16(Bg1 + k0, lB1);
        __syncthreads();
        bf16x8 a[4], b[4];
#pragma unroll
        for (int i = 0; i < 4; ++i) a[i] = *(const bf16x8*)(As + aoff[i]);
#pragma unroll
        for (int i = 0; i < 4; ++i) b[i] = *(const bf16x8*)(Bs + boff[i]);
#pragma unroll
        for (int mi = 0; mi < 4; ++mi)
#pragma unroll
            for (int ni = 0; ni < 4; ++ni)
                acc[mi][ni] = __builtin_amdgcn_mfma_f32_16x16x32_bf16(
                    a[mi], b[ni], acc[mi][ni], 0, 0, 0);
        __syncthreads();
    }
    const int rbase = lq * 4;
#pragma unroll
    for (int mi = 0; mi < 4; ++mi)
#pragma unroll
        for (int ni = 0; ni < 4; ++ni) {
            int col = nB + wn + ni * 16 + lr;
#pragma unroll
            for (int r = 0; r < 4; ++r) {
                int row = mB + wm + mi * 16 + rbase + r;
                C[(size_t)row * ldc + col] = f2bf(acc[mi][ni][r]);
            }
        }
}

// ---------------------------------------------------------------------------
// Final GEMM (128-tile): out[r,o] = v1[perm(r),:]·Wf[o,:512]
//   + h1[r,:]·Wf[o,512:] + bias[o]; fp32 out. M=8192, N=512, K=1024.
// ---------------------------------------------------------------------------
__global__ __launch_bounds__(256) void gemm128_final(
    const unsigned short* __restrict__ V1, const unsigned short* __restrict__ H1,
    const unsigned short* __restrict__ W, const float* __restrict__ bias,
    float* __restrict__ C)
{
    __shared__ unsigned short As[128 * 32];
    __shared__ unsigned short Bs[128 * 32];
    const int tid = threadIdx.x, wave = tid >> 6, lane = tid & 63;
    const int mB = blockIdx.x * 128, nB = blockIdx.y * 128;
    const int wm = (wave >> 1) * 64, wn = (wave & 1) * 64;
    const int lr = lane & 15, lq = lane >> 4;
    const int s0 = wave * 64 + lane, s1 = s0 + 256;
    const int row0 = s0 >> 2, q0 = (s0 & 3) ^ ((row0 >> 1) & 3);
    const int row1 = s1 >> 2, q1 = (s1 & 3) ^ ((row1 >> 1) & 3);
    const int r0g = mB + row0, r1g = mB + row1;
    const int pr0 = (r0g & ~4095) | ((r0g & 63) << 6) | ((r0g >> 6) & 63);
    const int pr1 = (r1g & ~4095) | ((r1g & 63) << 6) | ((r1g >> 6) & 63);
    const unsigned short* Bg0 = W + (size_t)(nB + row0) * 1024 + q0 * 8;
    const unsigned short* Bg1 = W + (size_t)(nB + row1) * 1024 + q1 * 8;
    unsigned short* lA0 = As + s0 * 8; unsigned short* lA1 = As + s1 * 8;
    unsigned short* lB0 = Bs + s0 * 8; unsigned short* lB1 = Bs + s1 * 8;
    const int sw = (lq ^ ((lr >> 1) & 3)) * 8;
    int aoff[4], boff[4];
#pragma unroll
    for (int i = 0; i < 4; ++i) {
        aoff[i] = (wm + i * 16 + lr) * 32 + sw;
        boff[i] = (wn + i * 16 + lr) * 32 + sw;
    }
    f32x4 zero4 = {0.f,0.f,0.f,0.f};
    f32x4 acc[4][4] = {{zero4,zero4,zero4,zero4},{zero4,zero4,zero4,zero4},
                       {zero4,zero4,zero4,zero4},{zero4,zero4,zero4,zero4}};
    for (int k0 = 0; k0 < 1024; k0 += 32) {
        int kk0 = k0 + q0 * 8, kk1 = k0 + q1 * 8;
        const unsigned short* g0 = (kk0 < 512) ? V1 + (size_t)pr0 * 512 + kk0
                                               : H1 + (size_t)r0g * 512 + (kk0 - 512);
        const unsigned short* g1 = (kk1 < 512) ? V1 + (size_t)pr1 * 512 + kk1
                                               : H1 + (size_t)r1g * 512 + (kk1 - 512);
        async_lds16(g0, lA0);
        async_lds16(g1, lA1);
        async_lds16(Bg0 + k0, lB0);
        async_lds16(Bg1 + k0, lB1);
        __syncthreads();
        bf16x8 a[4], b[4];
#pragma unroll
        for (int i = 0; i < 4; ++i) a[i] = *(const bf16x8*)(As + aoff[i]);
#pragma unroll
        for (int i = 0; i < 4; ++i) b[i] = *(const bf16x8*)(Bs + boff[i]);
#pragma unroll
        for (int mi = 0; mi < 4; ++mi)
#pragma unroll
            for (int ni = 0; ni < 4; ++ni)
                acc[mi][ni] = __builtin_amdgcn_mfma_f32_16x16x32_bf16(
                    a[mi], b[ni], acc[mi][ni], 0, 0, 0);
        __syncthreads();
    }
    const int rbase = lq * 4;
#pragma unroll
    for (int mi = 0; mi < 4; ++mi)
#pragma unroll
        for (int ni = 0; ni < 4; ++ni) {
            int col = nB + wn + ni * 16 + lr;
            float bb = bias[col];
#pragma unroll
            for (int r = 0; r < 4; ++r) {
                int row = mB + wm + mi * 16 + rbase + r;
                C[(size_t)row * 512 + col] = acc[mi][ni][r] + bb;
            }
        }
}

// ---------------------------------------------------------------------------
// dt path fully in fp32. Block = (seq, head-quad): 512 blocks.
// ---------------------------------------------------------------------------
__global__ __launch_bounds__(256) void dt_cs(
    const float* __restrict__ x, const float* __restrict__ in_w,
    const float* __restrict__ dt_bias, const float* __restrict__ A_log,
    float* __restrict__ dtb, float* __restrict__ csb, int dir)
{
    __shared__ float wsm[4][512];
    __shared__ float xs[64][68];
    __shared__ float dta[4][64], dtt[4][64];
    const int tid = threadIdx.x;
    const int seq = blockIdx.x >> 2, hq = blockIdx.x & 3;
#pragma unroll
    for (int i = 0; i < 2; ++i) {
        int slot = tid + i * 256;
        int h = slot >> 7, c = (slot & 127) * 4;
        *(float4*)&wsm[h][c] = *(const float4*)(in_w + (size_t)(2304 + hq * 4 + h) * 512 + c);
    }
    const int t = tid & 63, hh = tid >> 6;
    const int h = hq * 4 + hh;
    float acc = 0.f;
    for (int c0 = 0; c0 < 512; c0 += 64) {
        __syncthreads();
#pragma unroll
        for (int i = 0; i < 4; ++i) {
            int slot = tid + i * 256;
            int r = slot >> 4, cc = (slot & 15) * 4;
            size_t row = (dir == 0) ? (size_t)seq * 64 + r
                                    : (size_t)(seq >> 6) * 4096 + (size_t)r * 64 + (seq & 63);
            *(float4*)&xs[r][cc] = *(const float4*)(x + row * 512 + c0 + cc);
        }
        __syncthreads();
#pragma unroll
        for (int cc = 0; cc < 64; cc += 4) {
            float4 u4 = *(const float4*)&xs[t][cc];
            const float* w = &wsm[hh][c0 + cc];
            acc += u4.x * w[0] + u4.y * w[1] + u4.z * w[2] + u4.w * w[3];
        }
    }
    float v = acc + dt_bias[h];
    float dtv = (v > 20.f) ? v : log1pf(__expf(v));
    dtt[hh][t] = dtv;
    dta[hh][t] = dtv * -__expf(A_log[h]);
    __syncthreads();
    if (tid < 4) {
        float run = 0.f;
        int ob = (seq * 16 + hq * 4 + tid) * 64;
        for (int tt = 0; tt < 64; ++tt) {
            run += dta[tid][tt];
            dtb[ob + tt] = dtt[tid][tt];
            csb[ob + tt] = run;
        }
    }
}

// ---------------------------------------------------------------------------
// Scan, 4 heads per block (512 blocks): G = C·B^T computed ONCE (in regs),
// then per head: Ms = G∘L(h)∘dt(h) -> y_h = Ms·X_h (MFMA) + D*x.
// ---------------------------------------------------------------------------
__global__ __launch_bounds__(256) void scan4(
    const unsigned short* __restrict__ xbc, const float* __restrict__ dtb,
    const float* __restrict__ csb, const float* __restrict__ Dv,
    unsigned short* __restrict__ y)
{
    __shared__ unsigned short Bs[64 * BCS];
    __shared__ unsigned short Cs[64 * BCS];
    __shared__ unsigned short XsT[4][64 * XMS];  // X_h transposed: [p][t]
    __shared__ unsigned short Ms[64 * XMS];
    __shared__ float dts[4][64], css[4][64];
    const int tid = threadIdx.x;
    const int lane = tid & 63, wave = tid >> 6;
    const int seq = blockIdx.x >> 2, hq = blockIdx.x & 3;
    {
        int h = tid >> 6, t = tid & 63;
        dts[h][t] = dtb[(seq * 16 + hq * 4 + h) * 64 + t];
        css[h][t] = csb[(seq * 16 + hq * 4 + h) * 64 + t];
    }
    const unsigned short* base = xbc + (size_t)seq * 64 * 1280;
#pragma unroll
    for (int i = 0; i < 4; ++i) {
        int e = (tid + i * 256) * 8;
        int r = e >> 7, c = e & 127;
        *(uint4*)(Bs + r * BCS + c) = *(const uint4*)(base + (size_t)r * 1280 + 1024 + c);
        *(uint4*)(Cs + r * BCS + c) = *(const uint4*)(base + (size_t)r * 1280 + 1152 + c);
    }
    // X staging for 4 heads (cols hq*256..+256), transposed with rotation
#pragma unroll
    for (int i = 0; i < 8; ++i) {
        int e = (tid + i * 256) * 8;          // 16384 elems
        int t = e >> 8, c0 = e & 255;
        int h = c0 >> 6, p0 = c0 & 63;
        uint4 xval = *(const uint4*)(base + (size_t)t * 1280 + hq * 256 + c0);
        const unsigned short* xsv = (const unsigned short*)&xval;
#pragma unroll
        for (int j = 0; j < 8; ++j) {
            int jl = (j + lane) & 7;
            XsT[h][(p0 + jl) * XMS + t] = xsv[jl];
        }
    }
    __syncthreads();
    const int lr = lane & 15, lq = lane >> 4;
    f32x4 zero4 = {0.f,0.f,0.f,0.f};
    // ---- G = C·B^T once; wave owns t-rows [wave*16,+16), all 64 s ----
    f32x4 acc[4] = {zero4, zero4, zero4, zero4};
#pragma unroll
    for (int kt = 0; kt < 4; ++kt) {
        bf16x8 a = *(const bf16x8*)(Cs + (wave * 16 + lr) * BCS + kt * 32 + lq * 8);
#pragma unroll
        for (int ni = 0; ni < 4; ++ni) {
            bf16x8 b = *(const bf16x8*)(Bs + (ni * 16 + lr) * BCS + kt * 32 + lq * 8);
            acc[ni] = __builtin_amdgcn_mfma_f32_16x16x32_bf16(a, b, acc[ni], 0, 0, 0);
        }
    }
    for (int h = 0; h < 4; ++h) {
        float css_t[4];
#pragma unroll
        for (int r = 0; r < 4; ++r) css_t[r] = css[h][wave * 16 + lq * 4 + r];
#pragma unroll
        for (int ni = 0; ni < 4; ++ni) {
            int s = ni * 16 + lr;
            float cs_s = css[h][s], dt_s = dts[h][s];
#pragma unroll
            for (int r = 0; r < 4; ++r) {
                int t = wave * 16 + lq * 4 + r;
                float e = __expf(fminf(css_t[r] - cs_s, 0.f));
                float m = (s <= t) ? acc[ni][r] * e * dt_s : 0.f;
                Ms[t * XMS + s] = f2bf(m);
            }
        }
        __syncthreads();
        f32x4 yacc[4] = {zero4, zero4, zero4, zero4};
#pragma unroll
        for (int kt = 0; kt < 2; ++kt) {
            bf16x8 a = *(const bf16x8*)(Ms + (wave * 16 + lr) * XMS + kt * 32 + lq * 8);
#pragma unroll
            for (int ni = 0; ni < 4; ++ni) {
                bf16x8 b = *(const bf16x8*)(XsT[h] + (ni * 16 + lr) * XMS + kt * 32 + lq * 8);
                yacc[ni] = __builtin_amdgcn_mfma_f32_16x16x32_bf16(a, b, yacc[ni], 0, 0, 0);
            }
        }
        const float Dh = Dv[hq * 4 + h];
        unsigned short* yout = y + (size_t)seq * 64 * 1024 + (hq * 4 + h) * 64;
#pragma unroll
        for (int ni = 0; ni < 4; ++ni) {
            int p = ni * 16 + lr;
#pragma unroll
            for (int r = 0; r < 4; ++r) {
                int t = wave * 16 + lq * 4 + r;
                float v = yacc[ni][r] + Dh * bf2f(XsT[h][p * XMS + t]);
                yout[(size_t)t * 1024 + p] = f2bf(v);
            }
        }
        __syncthreads();   // Ms reused next head
    }
}

// ---------------------------------------------------------------------------
// Gate with silu(z) + RMSNorm over 1024 channels, in-place on y (bf16).
// ---------------------------------------------------------------------------
__global__ __launch_bounds__(128) void gate_norm(
    const unsigned short* __restrict__ z, unsigned short* __restrict__ y,
    const float* __restrict__ nw)
{
    const int row = blockIdx.x, tid = threadIdx.x;
    uint4 yv4 = *(const uint4*)(y + (size_t)row * 1024 + tid * 8);
    uint4 zv4 = *(const uint4*)(z + (size_t)row * 1024 + tid * 8);
    const unsigned short* ys = (const unsigned short*)&yv4;
    const unsigned short* zs = (const unsigned short*)&zv4;
    float g[8]; float ss = 0.f;
#pragma unroll
    for (int j = 0; j < 8; ++j) {
        float zv = bf2f(zs[j]);
        float gv = bf2f(ys[j]) * (zv / (1.f + __expf(-zv)));
        g[j] = gv; ss += gv * gv;
    }
#pragma unroll
    for (int off = 32; off > 0; off >>= 1) ss += __shfl_xor(ss, off, 64);
    __shared__ float red[2];
    if ((tid & 63) == 0) red[tid >> 6] = ss;
    __syncthreads();
    ss = red[0] + red[1];
    const float scale = rsqrtf(ss * (1.f / 1024.f) + 1e-5f);
    unsigned short out8[8] __attribute__((aligned(16)));
#pragma unroll
    for (int j = 0; j < 8; ++j) out8[j] = f2bf(g[j] * scale * nw[tid * 8 + j]);
    *(uint4*)(y + (size_t)row * 1024 + tid * 8) = *(const uint4*)out8;
}

// xv[(b,w,h)] row <- xbf[(b,h,w)] row (bf16, 16B chunks)
__global__ void transpose_hw(const unsigned short* __restrict__ x,
                             unsigned short* __restrict__ xv)
{
    int idx = blockIdx.x * 256 + threadIdx.x;
    if (idx >= NROWS * 64) return;
    int chunk = idx & 63;
    int r = idx >> 6;
    int hh = r & 63, w = (r >> 6) & 63, b = r >> 12;
    int src = b * 4096 + hh * 64 + w;
    *(uint4*)(xv + (size_t)r * 512 + chunk * 8) =
        *(const uint4*)(x + (size_t)src * 512 + chunk * 8);
}

// Wf[o,c<512] = fcw[o,c]+fcw[o,512+c]; Wf[o,512+c] = fcw[o,1024+c]+fcw[o,1536+c]
__global__ void fold_w(const float* __restrict__ fcw, unsigned short* __restrict__ wf)
{
    int idx = blockIdx.x * 256 + threadIdx.x;
    if (idx >= 512 * 1024) return;
    int o = idx >> 10, c = idx & 1023;
    int half = c >> 9, cc = c & 511;
    float v = fcw[(size_t)o * 2048 + half * 1024 + cc] +
              fcw[(size_t)o * 2048 + half * 1024 + 512 + cc];
    wf[idx] = f2bf(v);
}

extern "C" void kernel_launch(void* const* d_in, const int* in_sizes, int n_in,
                              void* d_out, int out_size, void* d_ws, size_t ws_size,
                              hipStream_t stream)
{
    (void)in_sizes; (void)n_in; (void)out_size; (void)ws_size;
    const float* x   = (const float*)d_in[0];
    const float* fcw = (const float*)d_in[17];
    const float* fcb = (const float*)d_in[18];

    char* ws = (char*)d_ws;
    size_t off = 0;
    auto alloc = [&](size_t bytes) {
        void* p = ws + off; off += (bytes + 255) & ~(size_t)255; return p;
    };
    unsigned short* xbf  = (unsigned short*)alloc((size_t)NROWS * 512 * 2);
    unsigned short* xv   = (unsigned short*)alloc((size_t)NROWS * 512 * 2);
    unsigned short* wbA  = (unsigned short*)alloc((size_t)2320 * 512 * 2);
    unsigned short* wbO  = (unsigned short*)alloc((size_t)512 * 1024 * 2);
    unsigned short* wf   = (unsigned short*)alloc((size_t)512 * 1024 * 2);
    unsigned short* zbuf = (unsigned short*)alloc((size_t)NROWS * 1024 * 2);
    unsigned short* xbc  = (unsigned short*)alloc((size_t)NROWS * 1280 * 2);
    float* dtb           = (float*)alloc((size_t)2048 * 64 * 4);
    float* csb           = (float*)alloc((size_t)2048 * 64 * 4);
    unsigned short* yb   = (unsigned short*)alloc((size_t)NROWS * 1024 * 2);
    unsigned short* h1   = (unsigned short*)alloc((size_t)NROWS * 512 * 2);
    unsigned short* v1   = (unsigned short*)alloc((size_t)NROWS * 512 * 2);

    cvt_bf16<<<(NROWS * 512 / 4 + 255) / 256, 256, 0, stream>>>(x, xbf, NROWS * 512 / 4);
    transpose_hw<<<(NROWS * 64) / 256, 256, 0, stream>>>(xbf, xv);
    fold_w<<<(512 * 1024) / 256, 256, 0, stream>>>(fcw, wf);

    for (int dir = 0; dir < 2; ++dir) {
        int p = dir == 0 ? 1 : 9;
        const float* in_w   = (const float*)d_in[p + 0];
        const float* conv_w = (const float*)d_in[p + 1];
        const float* conv_b = (const float*)d_in[p + 2];
        const float* A_log  = (const float*)d_in[p + 3];
        const float* dt_b   = (const float*)d_in[p + 4];
        const float* Dvec   = (const float*)d_in[p + 5];
        const float* nw     = (const float*)d_in[p + 6];
        const float* out_w  = (const float*)d_in[p + 7];

        cvt_bf16<<<(2320 * 512 / 4 + 255) / 256, 256, 0, stream>>>(in_w, wbA, 2320 * 512 / 4);
        cvt_bf16<<<(512 * 1024 / 4 + 255) / 256, 256, 0, stream>>>(out_w, wbO, 512 * 1024 / 4);

        const unsigned short* U = (dir == 0) ? xbf : xv;
        gemm_inproj<<<dim3(64, 18), 256, 0, stream>>>(U, wbA, zbuf, xbc, conv_w, conv_b);
        dt_cs<<<512, 256, 0, stream>>>(x, in_w, dt_b, A_log, dtb, csb, dir);
        scan4<<<512, 256, 0, stream>>>(xbc, dtb, csb, Dvec, yb);
        gate_norm<<<NROWS, 128, 0, stream>>>(zbuf, yb, nw);
        gemm128_bt<<<dim3(64, 4), 256, 0, stream>>>(yb, wbO, dir == 0 ? h1 : v1,
                                                    1024, 1024, 1024, 512);
    }
    gemm128_final<<<dim3(64, 4), 256, 0, stream>>>(v1, h1, wf, fcb, (float*)d_out);
}

// Round 6
// 363.161 us; speedup vs baseline: 1.2744x; 1.2744x over previous
//
#include <hip/hip_runtime.h>

#define NROWS 8192      // 128 sequences * 64 positions
#define NZX   2304      // z (1024) + xBC (1280) columns from in-proj
#define BCS   136       // Bs/Cs LDS row stride (elements, padded)
#define XMS   72        // XsT/Ms LDS row stride (elements, padded)

typedef __attribute__((ext_vector_type(8))) short bf16x8;
typedef __attribute__((ext_vector_type(4))) float f32x4;

__device__ __forceinline__ float bf2f(unsigned short u) {
    union { unsigned int i; float f; } v; v.i = ((unsigned int)u) << 16; return v.f;
}
__device__ __forceinline__ unsigned short f2bf(float f) {
    union { float f; unsigned int i; } v; v.f = f;
    unsigned int r = v.i + 0x7FFFu + ((v.i >> 16) & 1u);
    return (unsigned short)(r >> 16);
}

// async global->LDS, 16B per lane; lane's LDS slot must be wave-base + lane*16.
__device__ __forceinline__ void async_lds16(const unsigned short* g, unsigned short* l) {
    __builtin_amdgcn_global_load_lds(
        (const __attribute__((address_space(1))) unsigned int*)g,
        (__attribute__((address_space(3))) unsigned int*)l, 16, 0, 0);
}

// fp32 -> bf16 conversion, 4 elements/thread
__global__ void cvt_bf16(const float* __restrict__ s, unsigned short* __restrict__ d, int n4)
{
    int i = blockIdx.x * 256 + threadIdx.x;
    if (i >= n4) return;
    float4 v = *(const float4*)(s + (size_t)i * 4);
    ushort4 o;
    o.x = f2bf(v.x); o.y = f2bf(v.y); o.z = f2bf(v.z); o.w = f2bf(v.w);
    *(ushort4*)(d + (size_t)i * 4) = o;
}

// fp32 [512][1024] -> bf16 transposed [1024][512], 64x64 LDS tiles.
// grid (8 o-tiles, 16 c-tiles), 256 threads.
__global__ __launch_bounds__(256) void cvtT_bf16(
    const float* __restrict__ s, unsigned short* __restrict__ d)
{
    __shared__ float T[64][65];
    const int tid = threadIdx.x;
    const int bo = blockIdx.x * 64, bc = blockIdx.y * 64;
#pragma unroll
    for (int i = 0; i < 16; ++i) {
        int slot = tid + i * 256;
        int r = slot >> 6, c = slot & 63;
        T[r][c] = s[(size_t)(bo + r) * 1024 + bc + c];
    }
    __syncthreads();
#pragma unroll
    for (int i = 0; i < 16; ++i) {
        int slot = tid + i * 256;
        int cr = slot >> 6, oc = slot & 63;   // out row = c, out col = o
        d[(size_t)(bc + cr) * 512 + bo + oc] = f2bf(T[oc][cr]);
    }
}

// ---------------------------------------------------------------------------
// 128x128 GEMM-BT: C[m,n] = sum_k A[m,k]*B[n,k], bf16 out.
// perm!=0 applies the (b,h,w)->(b,w,h) row permutation to A reads.
// ---------------------------------------------------------------------------
__global__ __launch_bounds__(256) void gemm128_bt(
    const unsigned short* __restrict__ A, const unsigned short* __restrict__ B,
    unsigned short* __restrict__ C, int K, int lda, int ldb, int ldc, int perm)
{
    __shared__ unsigned short As[128 * 32];
    __shared__ unsigned short Bs[128 * 32];
    const int tid = threadIdx.x, wave = tid >> 6, lane = tid & 63;
    const int mB = blockIdx.x * 128, nB = blockIdx.y * 128;
    const int wm = (wave >> 1) * 64, wn = (wave & 1) * 64;
    const int lr = lane & 15, lq = lane >> 4;
    const int s0 = wave * 64 + lane, s1 = s0 + 256;
    const int row0 = s0 >> 2, q0 = (s0 & 3) ^ ((row0 >> 1) & 3);
    const int row1 = s1 >> 2, q1 = (s1 & 3) ^ ((row1 >> 1) & 3);
    int ar0 = mB + row0, ar1 = mB + row1;
    if (perm) {
        ar0 = (ar0 & ~4095) | ((ar0 & 63) << 6) | ((ar0 >> 6) & 63);
        ar1 = (ar1 & ~4095) | ((ar1 & 63) << 6) | ((ar1 >> 6) & 63);
    }
    const unsigned short* Ag0 = A + (size_t)ar0 * lda + q0 * 8;
    const unsigned short* Ag1 = A + (size_t)ar1 * lda + q1 * 8;
    const unsigned short* Bg0 = B + (size_t)(nB + row0) * ldb + q0 * 8;
    const unsigned short* Bg1 = B + (size_t)(nB + row1) * ldb + q1 * 8;
    unsigned short* lA0 = As + s0 * 8; unsigned short* lA1 = As + s1 * 8;
    unsigned short* lB0 = Bs + s0 * 8; unsigned short* lB1 = Bs + s1 * 8;
    const int sw = (lq ^ ((lr >> 1) & 3)) * 8;
    int aoff[4], boff[4];
#pragma unroll
    for (int i = 0; i < 4; ++i) {
        aoff[i] = (wm + i * 16 + lr) * 32 + sw;
        boff[i] = (wn + i * 16 + lr) * 32 + sw;
    }
    f32x4 zero4 = {0.f,0.f,0.f,0.f};
    f32x4 acc[4][4] = {{zero4,zero4,zero4,zero4},{zero4,zero4,zero4,zero4},
                       {zero4,zero4,zero4,zero4},{zero4,zero4,zero4,zero4}};
    for (int k0 = 0; k0 < K; k0 += 32) {
        async_lds16(Ag0 + k0, lA0);
        async_lds16(Ag1 + k0, lA1);
        async_lds16(Bg0 + k0, lB0);
        async_lds16(Bg1 + k0, lB1);
        __syncthreads();
        bf16x8 a[4], b[4];
#pragma unroll
        for (int i = 0; i < 4; ++i) a[i] = *(const bf16x8*)(As + aoff[i]);
#pragma unroll
        for (int i = 0; i < 4; ++i) b[i] = *(const bf16x8*)(Bs + boff[i]);
#pragma unroll
        for (int mi = 0; mi < 4; ++mi)
#pragma unroll
            for (int ni = 0; ni < 4; ++ni)
                acc[mi][ni] = __builtin_amdgcn_mfma_f32_16x16x32_bf16(
                    a[mi], b[ni], acc[mi][ni], 0, 0, 0);
        __syncthreads();
    }
    const int rbase = lq * 4;
#pragma unroll
    for (int mi = 0; mi < 4; ++mi)
#pragma unroll
        for (int ni = 0; ni < 4; ++ni) {
            int col = nB + wn + ni * 16 + lr;
#pragma unroll
            for (int r = 0; r < 4; ++r) {
                int row = mB + wm + mi * 16 + rbase + r;
                C[(size_t)row * ldc + col] = f2bf(acc[mi][ni][r]);
            }
        }
}

// ---------------------------------------------------------------------------
// Final GEMM: out[r,o] = sum_{k<1024} yv[perm(r),k]*Wc[o,k]
//                      + sum_{k>=1024} yh[r,k-1024]*Wc[o,k] + bias[o]; fp32.
// M=8192, N=512, K=2048. Wc ld 2048.
// ---------------------------------------------------------------------------
__global__ __launch_bounds__(256) void gemm_final2048(
    const unsigned short* __restrict__ YV, const unsigned short* __restrict__ YH,
    const unsigned short* __restrict__ W, const float* __restrict__ bias,
    float* __restrict__ C)
{
    __shared__ unsigned short As[128 * 32];
    __shared__ unsigned short Bs[128 * 32];
    const int tid = threadIdx.x, wave = tid >> 6, lane = tid & 63;
    const int mB = blockIdx.x * 128, nB = blockIdx.y * 128;
    const int wm = (wave >> 1) * 64, wn = (wave & 1) * 64;
    const int lr = lane & 15, lq = lane >> 4;
    const int s0 = wave * 64 + lane, s1 = s0 + 256;
    const int row0 = s0 >> 2, q0 = (s0 & 3) ^ ((row0 >> 1) & 3);
    const int row1 = s1 >> 2, q1 = (s1 & 3) ^ ((row1 >> 1) & 3);
    const int r0g = mB + row0, r1g = mB + row1;
    const int pr0 = (r0g & ~4095) | ((r0g & 63) << 6) | ((r0g >> 6) & 63);
    const int pr1 = (r1g & ~4095) | ((r1g & 63) << 6) | ((r1g >> 6) & 63);
    const unsigned short* Bg0 = W + (size_t)(nB + row0) * 2048 + q0 * 8;
    const unsigned short* Bg1 = W + (size_t)(nB + row1) * 2048 + q1 * 8;
    unsigned short* lA0 = As + s0 * 8; unsigned short* lA1 = As + s1 * 8;
    unsigned short* lB0 = Bs + s0 * 8; unsigned short* lB1 = Bs + s1 * 8;
    const int sw = (lq ^ ((lr >> 1) & 3)) * 8;
    int aoff[4], boff[4];
#pragma unroll
    for (int i = 0; i < 4; ++i) {
        aoff[i] = (wm + i * 16 + lr) * 32 + sw;
        boff[i] = (wn + i * 16 + lr) * 32 + sw;
    }
    f32x4 zero4 = {0.f,0.f,0.f,0.f};
    f32x4 acc[4][4] = {{zero4,zero4,zero4,zero4},{zero4,zero4,zero4,zero4},
                       {zero4,zero4,zero4,zero4},{zero4,zero4,zero4,zero4}};
    for (int k0 = 0; k0 < 2048; k0 += 32) {
        int kk0 = k0 + q0 * 8, kk1 = k0 + q1 * 8;
        const unsigned short* g0 = (kk0 < 1024) ? YV + (size_t)pr0 * 1024 + kk0
                                                : YH + (size_t)r0g * 1024 + (kk0 - 1024);
        const unsigned short* g1 = (kk1 < 1024) ? YV + (size_t)pr1 * 1024 + kk1
                                                : YH + (size_t)r1g * 1024 + (kk1 - 1024);
        async_lds16(g0, lA0);
        async_lds16(g1, lA1);
        async_lds16(Bg0 + k0, lB0);
        async_lds16(Bg1 + k0, lB1);
        __syncthreads();
        bf16x8 a[4], b[4];
#pragma unroll
        for (int i = 0; i < 4; ++i) a[i] = *(const bf16x8*)(As + aoff[i]);
#pragma unroll
        for (int i = 0; i < 4; ++i) b[i] = *(const bf16x8*)(Bs + boff[i]);
#pragma unroll
        for (int mi = 0; mi < 4; ++mi)
#pragma unroll
            for (int ni = 0; ni < 4; ++ni)
                acc[mi][ni] = __builtin_amdgcn_mfma_f32_16x16x32_bf16(
                    a[mi], b[ni], acc[mi][ni], 0, 0, 0);
        __syncthreads();
    }
    const int rbase = lq * 4;
#pragma unroll
    for (int mi = 0; mi < 4; ++mi)
#pragma unroll
        for (int ni = 0; ni < 4; ++ni) {
            int col = nB + wn + ni * 16 + lr;
            float bb = bias[col];
#pragma unroll
            for (int r = 0; r < 4; ++r) {
                int row = mB + wm + mi * 16 + rbase + r;
                C[(size_t)row * 512 + col] = acc[mi][ni][r] + bb;
            }
        }
}

// ---------------------------------------------------------------------------
// Causal depthwise conv (k=4) + bias + SiLU. Block = (seq, 320-ch tile):
// stage 64x320 slab in LDS once, weights in regs, 8 rows/thread.
// ---------------------------------------------------------------------------
__global__ __launch_bounds__(320) void conv_silu(
    const unsigned short* __restrict__ zx, const float* __restrict__ cw,
    const float* __restrict__ cb, unsigned short* __restrict__ xbc)
{
    __shared__ unsigned short S[64 * 320];
    const int tid = threadIdx.x;
    const int seq = blockIdx.x >> 2, tile = blockIdx.x & 3;
    const int cbase = tile * 320;
    const unsigned short* src = zx + (size_t)seq * 64 * NZX + 1024 + cbase;
#pragma unroll
    for (int i = 0; i < 8; ++i) {
        int slot = tid + i * 320;
        int r = slot / 40, ch = (slot % 40) * 8;
        *(uint4*)(S + r * 320 + ch) = *(const uint4*)(src + (size_t)r * NZX + ch);
    }
    __syncthreads();
    const int c8 = (tid % 40) * 8, rg = tid / 40;
    const int gc = cbase + c8;
    float4 b0 = *(const float4*)(cb + gc), b1 = *(const float4*)(cb + gc + 4);
    const float bias[8] = {b0.x,b0.y,b0.z,b0.w,b1.x,b1.y,b1.z,b1.w};
    float4 wv[8];
#pragma unroll
    for (int j = 0; j < 8; ++j) wv[j] = *(const float4*)(cw + (size_t)(gc + j) * 4);
    unsigned short* dst = xbc + (size_t)seq * 64 * 1280 + gc;
#pragma unroll
    for (int r = 0; r < 8; ++r) {
        int t = rg * 8 + r;
        float acc[8];
#pragma unroll
        for (int j = 0; j < 8; ++j) acc[j] = bias[j];
#pragma unroll
        for (int k = 0; k < 4; ++k) {
            int ts = t + k - 3;
            if (ts >= 0) {
                uint4 xv = *(const uint4*)(S + ts * 320 + c8);
                const unsigned short* xs = (const unsigned short*)&xv;
#pragma unroll
                for (int j = 0; j < 8; ++j)
                    acc[j] += bf2f(xs[j]) * ((const float*)&wv[j])[k];
            }
        }
        unsigned short out8[8] __attribute__((aligned(16)));
#pragma unroll
        for (int j = 0; j < 8; ++j) out8[j] = f2bf(acc[j] / (1.f + __expf(-acc[j])));
        *(uint4*)(dst + (size_t)t * 1280) = *(const uint4*)out8;
    }
}

// ---------------------------------------------------------------------------
// dt path fully in fp32. Block = (seq, head-quad): 512 blocks.
// ---------------------------------------------------------------------------
__global__ __launch_bounds__(256) void dt_cs(
    const float* __restrict__ x, const float* __restrict__ in_w,
    const float* __restrict__ dt_bias, const float* __restrict__ A_log,
    float* __restrict__ dtb, float* __restrict__ csb, int dir)
{
    __shared__ float wsm[4][512];
    __shared__ float xs[64][68];
    __shared__ float dta[4][64], dtt[4][64];
    const int tid = threadIdx.x;
    const int seq = blockIdx.x >> 2, hq = blockIdx.x & 3;
#pragma unroll
    for (int i = 0; i < 2; ++i) {
        int slot = tid + i * 256;
        int h = slot >> 7, c = (slot & 127) * 4;
        *(float4*)&wsm[h][c] = *(const float4*)(in_w + (size_t)(2304 + hq * 4 + h) * 512 + c);
    }
    const int t = tid & 63, hh = tid >> 6;
    const int h = hq * 4 + hh;
    float acc = 0.f;
    for (int c0 = 0; c0 < 512; c0 += 64) {
        __syncthreads();
#pragma unroll
        for (int i = 0; i < 4; ++i) {
            int slot = tid + i * 256;
            int r = slot >> 4, cc = (slot & 15) * 4;
            size_t row = (dir == 0) ? (size_t)seq * 64 + r
                                    : (size_t)(seq >> 6) * 4096 + (size_t)r * 64 + (seq & 63);
            *(float4*)&xs[r][cc] = *(const float4*)(x + row * 512 + c0 + cc);
        }
        __syncthreads();
#pragma unroll
        for (int cc = 0; cc < 64; cc += 4) {
            float4 u4 = *(const float4*)&xs[t][cc];
            const float* w = &wsm[hh][c0 + cc];
            acc += u4.x * w[0] + u4.y * w[1] + u4.z * w[2] + u4.w * w[3];
        }
    }
    float v = acc + dt_bias[h];
    float dtv = (v > 20.f) ? v : log1pf(__expf(v));
    dtt[hh][t] = dtv;
    dta[hh][t] = dtv * -__expf(A_log[h]);
    __syncthreads();
    if (tid < 4) {
        float run = 0.f;
        int ob = (seq * 16 + hq * 4 + tid) * 64;
        for (int tt = 0; tt < 64; ++tt) {
            run += dta[tid][tt];
            dtb[ob + tt] = dtt[tid][tt];
            csb[ob + tt] = run;
        }
    }
}

// ---------------------------------------------------------------------------
// Scan: per (seq, head). Phase1: G = Cm·Bm^T (MFMA, K=128); decay/mask/dt in
// regs; Phase2: y = M·X (MFMA, K=64) + D*x. 256 threads, 2048 blocks.
// ---------------------------------------------------------------------------
__global__ __launch_bounds__(256) void scan_kernel(
    const unsigned short* __restrict__ xbc, const float* __restrict__ dtb,
    const float* __restrict__ csb, const float* __restrict__ Dv,
    unsigned short* __restrict__ y)
{
    __shared__ unsigned short Bs[64 * BCS];
    __shared__ unsigned short Cs[64 * BCS];
    __shared__ unsigned short XsT[64 * XMS];
    __shared__ unsigned short Ms[64 * XMS];
    __shared__ float dts[64], css[64];
    const int tid = threadIdx.x;
    const int lane = tid & 63, wave = tid >> 6;
    const int seq = blockIdx.x >> 4, h = blockIdx.x & 15;
    if (tid < 64) {
        dts[tid] = dtb[(seq * 16 + h) * 64 + tid];
        css[tid] = csb[(seq * 16 + h) * 64 + tid];
    }
    const unsigned short* base = xbc + (size_t)seq * 64 * 1280;
#pragma unroll
    for (int i = 0; i < 4; ++i) {
        int e = (tid + i * 256) * 8;
        int r = e >> 7, c = e & 127;
        *(uint4*)(Bs + r * BCS + c) = *(const uint4*)(base + (size_t)r * 1280 + 1024 + c);
        *(uint4*)(Cs + r * BCS + c) = *(const uint4*)(base + (size_t)r * 1280 + 1152 + c);
    }
#pragma unroll
    for (int i = 0; i < 2; ++i) {
        int e = (tid + i * 256) * 8;
        int t = e >> 6, p0 = e & 63;
        uint4 xval = *(const uint4*)(base + (size_t)t * 1280 + h * 64 + p0);
        const unsigned short* xs = (const unsigned short*)&xval;
#pragma unroll
        for (int j = 0; j < 8; ++j) {
            int jl = (j + lane) & 7;
            XsT[(p0 + jl) * XMS + t] = xs[jl];
        }
    }
    __syncthreads();
    const int lr = lane & 15, lq = lane >> 4;
    f32x4 zero4 = {0.f,0.f,0.f,0.f};
    f32x4 acc[4] = {zero4, zero4, zero4, zero4};
#pragma unroll
    for (int kt = 0; kt < 4; ++kt) {
        bf16x8 a = *(const bf16x8*)(Cs + (wave * 16 + lr) * BCS + kt * 32 + lq * 8);
#pragma unroll
        for (int ni = 0; ni < 4; ++ni) {
            bf16x8 b = *(const bf16x8*)(Bs + (ni * 16 + lr) * BCS + kt * 32 + lq * 8);
            acc[ni] = __builtin_amdgcn_mfma_f32_16x16x32_bf16(a, b, acc[ni], 0, 0, 0);
        }
    }
    float css_t[4];
#pragma unroll
    for (int r = 0; r < 4; ++r) css_t[r] = css[wave * 16 + lq * 4 + r];
#pragma unroll
    for (int ni = 0; ni < 4; ++ni) {
        int s = ni * 16 + lr;
        float cs_s = css[s], dt_s = dts[s];
#pragma unroll
        for (int r = 0; r < 4; ++r) {
            int t = wave * 16 + lq * 4 + r;
            float e = __expf(fminf(css_t[r] - cs_s, 0.f));
            float m = (s <= t) ? acc[ni][r] * e * dt_s : 0.f;
            Ms[t * XMS + s] = f2bf(m);
        }
    }
    __syncthreads();
    f32x4 yacc[4] = {zero4, zero4, zero4, zero4};
#pragma unroll
    for (int kt = 0; kt < 2; ++kt) {
        bf16x8 a = *(const bf16x8*)(Ms + (wave * 16 + lr) * XMS + kt * 32 + lq * 8);
#pragma unroll
        for (int ni = 0; ni < 4; ++ni) {
            bf16x8 b = *(const bf16x8*)(XsT + (ni * 16 + lr) * XMS + kt * 32 + lq * 8);
            yacc[ni] = __builtin_amdgcn_mfma_f32_16x16x32_bf16(a, b, yacc[ni], 0, 0, 0);
        }
    }
    const float Dh = Dv[h];
    unsigned short* yout = y + (size_t)seq * 64 * 1024 + h * 64;
#pragma unroll
    for (int ni = 0; ni < 4; ++ni) {
        int p = ni * 16 + lr;
#pragma unroll
        for (int r = 0; r < 4; ++r) {
            int t = wave * 16 + lq * 4 + r;
            float v = yacc[ni][r] + Dh * bf2f(XsT[p * XMS + t]);
            yout[(size_t)t * 1024 + p] = f2bf(v);
        }
    }
}

// ---------------------------------------------------------------------------
// Gate with silu(z) + RMSNorm over 1024 channels, in-place on y (bf16).
// z read from zx (ld NZX).
// ---------------------------------------------------------------------------
__global__ __launch_bounds__(128) void gate_norm(
    const unsigned short* __restrict__ zx, unsigned short* __restrict__ y,
    const float* __restrict__ nw)
{
    const int row = blockIdx.x, tid = threadIdx.x;
    uint4 yv4 = *(const uint4*)(y + (size_t)row * 1024 + tid * 8);
    uint4 zv4 = *(const uint4*)(zx + (size_t)row * NZX + tid * 8);
    const unsigned short* ys = (const unsigned short*)&yv4;
    const unsigned short* zs = (const unsigned short*)&zv4;
    float g[8]; float ss = 0.f;
#pragma unroll
    for (int j = 0; j < 8; ++j) {
        float zv = bf2f(zs[j]);
        float gv = bf2f(ys[j]) * (zv / (1.f + __expf(-zv)));
        g[j] = gv; ss += gv * gv;
    }
#pragma unroll
    for (int off = 32; off > 0; off >>= 1) ss += __shfl_xor(ss, off, 64);
    __shared__ float red[2];
    if ((tid & 63) == 0) red[tid >> 6] = ss;
    __syncthreads();
    ss = red[0] + red[1];
    const float scale = rsqrtf(ss * (1.f / 1024.f) + 1e-5f);
    unsigned short out8[8] __attribute__((aligned(16)));
#pragma unroll
    for (int j = 0; j < 8; ++j) out8[j] = f2bf(g[j] * scale * nw[tid * 8 + j]);
    *(uint4*)(y + (size_t)row * 1024 + tid * 8) = *(const uint4*)out8;
}

// Wf[o,c<512] = fcw[o,c]+fcw[o,512+c]; Wf[o,512+c] = fcw[o,1024+c]+fcw[o,1536+c]
__global__ void fold_w(const float* __restrict__ fcw, unsigned short* __restrict__ wf)
{
    int idx = blockIdx.x * 256 + threadIdx.x;
    if (idx >= 512 * 1024) return;
    int o = idx >> 10, c = idx & 1023;
    int half = c >> 9, cc = c & 511;
    float v = fcw[(size_t)o * 2048 + half * 1024 + cc] +
              fcw[(size_t)o * 2048 + half * 1024 + 512 + cc];
    wf[idx] = f2bf(v);
}

extern "C" void kernel_launch(void* const* d_in, const int* in_sizes, int n_in,
                              void* d_out, int out_size, void* d_ws, size_t ws_size,
                              hipStream_t stream)
{
    (void)in_sizes; (void)n_in; (void)out_size; (void)ws_size;
    const float* x   = (const float*)d_in[0];
    const float* fcw = (const float*)d_in[17];
    const float* fcb = (const float*)d_in[18];

    char* ws = (char*)d_ws;
    size_t off = 0;
    auto alloc = [&](size_t bytes) {
        void* p = ws + off; off += (bytes + 255) & ~(size_t)255; return p;
    };
    unsigned short* xbf   = (unsigned short*)alloc((size_t)NROWS * 512 * 2);
    unsigned short* wbA   = (unsigned short*)alloc((size_t)2320 * 512 * 2);
    unsigned short* wbOT  = (unsigned short*)alloc((size_t)1024 * 512 * 2);
    unsigned short* wf    = (unsigned short*)alloc((size_t)512 * 1024 * 2);
    unsigned short* wcomb = (unsigned short*)alloc((size_t)512 * 2048 * 2);
    unsigned short* zx    = (unsigned short*)alloc((size_t)NROWS * NZX * 2);
    unsigned short* xbc   = (unsigned short*)alloc((size_t)NROWS * 1280 * 2);
    float* dtb            = (float*)alloc((size_t)2048 * 64 * 4);
    float* csb            = (float*)alloc((size_t)2048 * 64 * 4);
    unsigned short* ybh   = (unsigned short*)alloc((size_t)NROWS * 1024 * 2);
    unsigned short* ybv   = (unsigned short*)alloc((size_t)NROWS * 1024 * 2);

    cvt_bf16<<<(NROWS * 512 / 4 + 255) / 256, 256, 0, stream>>>(x, xbf, NROWS * 512 / 4);
    fold_w<<<(512 * 1024) / 256, 256, 0, stream>>>(fcw, wf);

    // Combined weights: Wc[:, k<1024] = Wf[:, :512] @ out_w_v  (v half),
    //                   Wc[:, k>=1024] = Wf[:, 512:] @ out_w_h (h half).
    for (int dir = 0; dir < 2; ++dir) {
        const float* out_w = (const float*)d_in[(dir == 0 ? 1 : 9) + 7];
        cvtT_bf16<<<dim3(8, 16), 256, 0, stream>>>(out_w, wbOT);
        // A = Wf half (512x512, lda 1024), B = out_w^T (1024x512, ldb 512)
        gemm128_bt<<<dim3(4, 8), 256, 0, stream>>>(
            wf + (dir == 0 ? 512 : 0), wbOT,
            wcomb + (dir == 0 ? 1024 : 0), 512, 1024, 512, 2048, 0);
    }

    for (int dir = 0; dir < 2; ++dir) {
        int p = dir == 0 ? 1 : 9;
        const float* in_w   = (const float*)d_in[p + 0];
        const float* conv_w = (const float*)d_in[p + 1];
        const float* conv_b = (const float*)d_in[p + 2];
        const float* A_log  = (const float*)d_in[p + 3];
        const float* dt_b   = (const float*)d_in[p + 4];
        const float* Dvec   = (const float*)d_in[p + 5];
        const float* nw     = (const float*)d_in[p + 6];

        cvt_bf16<<<(2320 * 512 / 4 + 255) / 256, 256, 0, stream>>>(in_w, wbA, 2320 * 512 / 4);

        unsigned short* yb = (dir == 0) ? ybh : ybv;
        gemm128_bt<<<dim3(64, 18), 256, 0, stream>>>(xbf, wbA, zx,
                                                     512, 512, 512, NZX, dir);
        conv_silu<<<512, 320, 0, stream>>>(zx, conv_w, conv_b, xbc);
        dt_cs<<<512, 256, 0, stream>>>(x, in_w, dt_b, A_log, dtb, csb, dir);
        scan_kernel<<<2048, 256, 0, stream>>>(xbc, dtb, csb, Dvec, yb);
        gate_norm<<<NROWS, 128, 0, stream>>>(zx, yb, nw);
    }
    gemm_final2048<<<dim3(64, 4), 256, 0, stream>>>(ybv, ybh, wcomb, fcb, (float*)d_out);
}